// Round 1
// baseline (37.597 us; speedup 1.0000x reference)
//
#include <hip/hip_runtime.h>

// MatchingNetwork_19662360281417
//
// Algebraic collapse: the reference's final einsum('btn,btv->btv', att, one_hot)
// sums the softmax-over-n attention weights (which sum to 1) against a one-hot
// of labels -> output == one_hot(labels, V) exactly (to f32 rounding of the
// softmax sum, ~1e-7 << 2e-2 threshold). Every other input is mathematically
// irrelevant to the output. The kernel is therefore a pure 262 MB write:
// zeros everywhere, 1.0f at (b, t, labels[b,t]).

#define BB 32
#define TT 64
#define VV 32000

// One block per (b,t) row. 256 threads, float4 stores (16 B/lane coalesced).
// V/4 = 8000 float4 per row -> 31.25 iters/thread (bound-checked).
__global__ __launch_bounds__(256) void onehot_write_kernel(
    const int* __restrict__ labels, float4* __restrict__ out) {
    const int row = blockIdx.x;                 // 0 .. B*T-1
    const int lab = labels[row];                // cached, 1 scalar read per block
    float4* rowp = out + (size_t)row * (VV / 4);
    for (int j = threadIdx.x; j < VV / 4; j += 256) {
        const int base = j << 2;
        float4 v;
        v.x = (base + 0 == lab) ? 1.0f : 0.0f;  // branchless: no scratch,
        v.y = (base + 1 == lab) ? 1.0f : 0.0f;  // no runtime-indexed vector
        v.z = (base + 2 == lab) ? 1.0f : 0.0f;
        v.w = (base + 3 == lab) ? 1.0f : 0.0f;
        rowp[j] = v;
    }
}

extern "C" void kernel_launch(void* const* d_in, const int* in_sizes, int n_in,
                              void* d_out, int out_size, void* d_ws, size_t ws_size,
                              hipStream_t stream) {
    // Input order per setup_inputs(): 0=support_set, 1=target_set, 2=labels, ...
    const int* labels = (const int*)d_in[2];
    float4* out = (float4*)d_out;
    onehot_write_kernel<<<dim3(BB * TT), dim3(256), 0, stream>>>(labels, out);
}